// Round 13
// baseline (7906.761 us; speedup 1.0000x reference)
//
#include <hip/hip_runtime.h>

#define SEQL   512
#define HID    2048
#define NCLS   10

typedef _Float16 f16x8 __attribute__((ext_vector_type(8)));
typedef float    f32x4 __attribute__((ext_vector_type(4)));

__device__ __forceinline__ float fast_tanh(float v) {
    float e = __expf(2.0f * v);
    return 1.0f - 2.0f / (e + 1.0f);
}

// Pack whh (fp32 row-major [col][k]) into fp16 MFMA fragments, two regions:
//   R [0,4MiB):  reg-pinned ksts 0..31:  frag(m,j,f,ln), col=m*64+j*16+(ln&15),
//                k0 = f*32 + (ln>>4)*8
//   P [4MiB,8MiB): LDS-pinned ksts 32..63: same but k0 = (f+32)*32 + (ln>>4)*8
__global__ void pack_w_kernel(const float* __restrict__ w, _Float16* __restrict__ o) {
    const int fid = blockIdx.x * 256 + threadIdx.x;   // 0..524287
    const int q   = fid & 262143;
    const int m  = q >> 13;
    const int r13 = q & 8191;
    const int j  = r13 >> 11;
    const int f  = (r13 >> 6) & 31;
    const int ln = r13 & 63;
    const int col = m * 64 + j * 16 + (ln & 15);
    const int k0  = ((fid < 262144 ? 0 : 32) + f) * 32 + (ln >> 4) * 8;
    const float* src = w + (size_t)col * HID + k0;
    f16x8 v;
    #pragma unroll
    for (int i = 0; i < 8; ++i) v[i] = (_Float16)src[i];
    *(f16x8*)(o + (size_t)fid * 8) = v;
}

__global__ void __launch_bounds__(256, 1)
rnn_main(const float* __restrict__ x, const float* __restrict__ whx,
         const _Float16* __restrict__ Wp, const float* __restrict__ bh,
         const float* __restrict__ wph, const float* __restrict__ bp,
         _Float16* __restrict__ h0, _Float16* __restrict__ h1,
         unsigned* __restrict__ ctr, float* __restrict__ out)
{
    // 128 KiB: LDS-pinned B ksts 32..63, frag-major: slot = j*2048 + f*64 + lane
    __shared__ uint4 ldsB[8192];
    __shared__ unsigned s_mslot;

    const int tid = threadIdx.x;

    // physical XCD id -> group; member slot via allocator (32 WGs/XCD: 1 WG/CU,
    // forced by the 128 KiB LDS footprint)
    int xcc;
    asm volatile("s_getreg_b32 %0, hwreg(HW_REG_XCC_ID)" : "=s"(xcc));
    const int g = xcc & 7;
    unsigned* alloc = ctr + g * 64;
    unsigned* flgA  = ctr + 512 + g * 1024;           // 32 member flags, 128B stride
    unsigned* flgB  = ctr + 512 + 8192 + g * 1024;    // sub-batch B flags
    if (tid == 0)
        s_mslot = __hip_atomic_fetch_add(alloc, 1u, __ATOMIC_RELAXED, __HIP_MEMORY_SCOPE_WORKGROUP);
    __syncthreads();
    const int m = (int)s_mslot;              // 0..31
    unsigned* myflgA = flgA + m * 32;
    unsigned* myflgB = flgB + m * 32;
    const int rowbase = g * 32;              // rows [rowbase,+16)=A, [+16,+32)=B
    const int colbase = m * 64;

    const int lane = tid & 63;
    const int j    = tid >> 6;               // wave 0..3: col-tile j (16 cols, full K)

    const uint4* P4 = (const uint4*)Wp;

    // ---- stage LDS-pinned B (ksts 32..63) ----
    for (int s5 = tid; s5 < 8192; s5 += 256)
        ldsB[s5] = P4[262144 + m * 8192 + s5];

    // ---- step 0: h = tanh(x[:,0]*whx + bh) for all 32 rows ----
    for (int i = tid; i < 32 * 64; i += 256) {
        const int r = i >> 6, c = i & 63;
        const int b = rowbase + r, jj = colbase + c;
        h0[(size_t)b * HID + jj] = (_Float16)fast_tanh(x[(size_t)b * SEQL] * whx[jj] + bh[jj]);
    }

    // ---- pin this wave's reg-B (ksts 0..31) : 32 frags = 128 VGPR ----
    const uint4* R4 = P4 + m * 8192 + j * 2048 + lane;
    f16x8 bReg[32];
    #pragma unroll
    for (int f = 0; f < 32; ++f) bReg[f] = *(const f16x8*)&R4[f * 64];

    // per-wave constants
    const int ecol = colbase + j * 16 + (lane & 15);    // C/D col = lane&15
    const float wxc = whx[ecol], bbc = bh[ecol];
    const int eroff = (lane >> 4) * 4;                  // + sub_rowbase + r
    // A-operand: row = sub_rowbase + (lane&15); kst f -> + f*32 + (lane>>4)*8
    const size_t aoffA = (size_t)(rowbase + (lane & 15)) * HID + (lane >> 4) * 8;
    const size_t aoffB = aoffA + (size_t)16 * HID;
    const uint4* bl = &ldsB[j * 2048 + lane];
    const unsigned* pollA = flgA + (lane & 31) * 32;
    const unsigned* pollB = flgB + (lane & 31) * 32;

    // prologue arrive: drain step-0 stores + ldsB staging, post both flags
    __syncthreads();
    if (tid == 0) {
        __hip_atomic_fetch_add(myflgA, 4u, __ATOMIC_RELAXED, __HIP_MEMORY_SCOPE_WORKGROUP);
        __hip_atomic_fetch_add(myflgB, 4u, __ATOMIC_RELAXED, __HIP_MEMORY_SCOPE_WORKGROUP);
    }

    for (int t = 1; t < SEQL; ++t) {
        const _Float16* hs = (t & 1) ? h0 : h1;
        _Float16*       hd = (t & 1) ? h1 : h0;
        const unsigned tgt = 4u * (unsigned)t;

        // keep reg-pinned B materialized (stop load sinking)
        #pragma unroll
        for (int f = 0; f < 32; ++f) asm volatile("" : "+v"(bReg[f]));

        // ============ sub-step A (rows rowbase..+16) — no intra-CU sync ======
        {
            float xv[4];
            #pragma unroll
            for (int r = 0; r < 4; ++r)
                xv[r] = x[(size_t)(rowbase + eroff + r) * SEQL + t];

            unsigned v;
            do {
                v = __hip_atomic_load(pollA, __ATOMIC_RELAXED, __HIP_MEMORY_SCOPE_AGENT);
            } while (!__all((int)(v >= tgt)));
            asm volatile("buffer_inv sc0" ::: "memory");   // fresh h via L2

            const _Float16* ap = hs + aoffA;
            f32x4 accR = {0.f,0.f,0.f,0.f}, accL = accR;
            #pragma unroll
            for (int f = 0; f < 32; ++f) {
                const f16x8 aR_ = *(const f16x8*)(ap + f * 32);          // kst f
                const f16x8 aL_ = *(const f16x8*)(ap + 1024 + f * 32);   // kst f+32
                const f16x8 bL_ = *(const f16x8*)&bl[f * 64];
                accR = __builtin_amdgcn_mfma_f32_16x16x32_f16(aR_, bReg[f], accR, 0, 0, 0);
                accL = __builtin_amdgcn_mfma_f32_16x16x32_f16(aL_, bL_,     accL, 0, 0, 0);
            }
            const f32x4 s = accR + accL;
            #pragma unroll
            for (int r = 0; r < 4; ++r) {
                const int br = rowbase + eroff + r;
                hd[(size_t)br * HID + ecol] =
                    (_Float16)fast_tanh(s[r] + xv[r] * wxc + bbc);
            }
            asm volatile("s_waitcnt vmcnt(0)" ::: "memory");  // stores at L2
            if (lane == 0)
                __hip_atomic_fetch_add(myflgA, 1u, __ATOMIC_RELAXED, __HIP_MEMORY_SCOPE_WORKGROUP);
        }

        // ============ sub-step B (rows rowbase+16..+32) ======================
        {
            float xv[4];
            #pragma unroll
            for (int r = 0; r < 4; ++r)
                xv[r] = x[(size_t)(rowbase + 16 + eroff + r) * SEQL + t];

            unsigned v;
            do {
                v = __hip_atomic_load(pollB, __ATOMIC_RELAXED, __HIP_MEMORY_SCOPE_AGENT);
            } while (!__all((int)(v >= tgt)));
            asm volatile("buffer_inv sc0" ::: "memory");

            const _Float16* ap = hs + aoffB;
            f32x4 accR = {0.f,0.f,0.f,0.f}, accL = accR;
            #pragma unroll
            for (int f = 0; f < 32; ++f) {
                const f16x8 aR_ = *(const f16x8*)(ap + f * 32);
                const f16x8 aL_ = *(const f16x8*)(ap + 1024 + f * 32);
                const f16x8 bL_ = *(const f16x8*)&bl[f * 64];
                accR = __builtin_amdgcn_mfma_f32_16x16x32_f16(aR_, bReg[f], accR, 0, 0, 0);
                accL = __builtin_amdgcn_mfma_f32_16x16x32_f16(aL_, bL_,     accL, 0, 0, 0);
            }
            const f32x4 s = accR + accL;
            #pragma unroll
            for (int r = 0; r < 4; ++r) {
                const int br = rowbase + 16 + eroff + r;
                hd[(size_t)br * HID + ecol] =
                    (_Float16)fast_tanh(s[r] + xv[r] * wxc + bbc);
            }
            asm volatile("s_waitcnt vmcnt(0)" ::: "memory");
            if (lane == 0)
                __hip_atomic_fetch_add(myflgB, 1u, __ATOMIC_RELAXED, __HIP_MEMORY_SCOPE_WORKGROUP);
        }
    }

    // final release: all t=511 stores visible, then L1 inv
    {
        const unsigned tgt = 4u * (unsigned)SEQL;
        unsigned v;
        do {
            v = __hip_atomic_load(pollA, __ATOMIC_RELAXED, __HIP_MEMORY_SCOPE_AGENT);
        } while (!__all((int)(v >= tgt)));
        do {
            v = __hip_atomic_load(pollB, __ATOMIC_RELAXED, __HIP_MEMORY_SCOPE_AGENT);
        } while (!__all((int)(v >= tgt)));
    }
    asm volatile("buffer_inv sc0" ::: "memory");

    // ---- projection: p = h_last @ wph.T + bp (member m -> row rowbase+m) ----
    const int brow = rowbase + m;
    const _Float16* hp = h1 + (size_t)brow * HID + lane * 32;
    for (int c = j; c < NCLS; c += 4) {
        const float* wp = wph + (size_t)c * HID + lane * 32;
        float psum = 0.f;
        #pragma unroll
        for (int i = 0; i < 32; ++i) psum += (float)hp[i] * wp[i];
        #pragma unroll
        for (int off = 32; off >= 1; off >>= 1) psum += __shfl_xor(psum, off, 64);
        if (lane == 0) out[brow * NCLS + c] = psum + bp[c];
    }
}

extern "C" void kernel_launch(void* const* d_in, const int* in_sizes, int n_in,
                              void* d_out, int out_size, void* d_ws, size_t ws_size,
                              hipStream_t stream) {
    const float* x   = (const float*)d_in[0];
    const float* whx = (const float*)d_in[1];
    const float* whh = (const float*)d_in[2];
    const float* bh  = (const float*)d_in[3];
    const float* wph = (const float*)d_in[4];
    const float* bp  = (const float*)d_in[5];
    float* out = (float*)d_out;

    char* ws = (char*)d_ws;
    _Float16* Wp  = (_Float16*)ws;                         // 8 MiB packed whh fp16 (R + P)
    _Float16* h0  = (_Float16*)(ws + (size_t)(8u << 20));  // 1 MiB  h buffer A
    _Float16* h1  = (_Float16*)(ws + (size_t)(9u << 20));  // 1 MiB  h buffer B
    unsigned* ctr = (unsigned*)(ws + (size_t)(10u << 20)); // 68 KiB alloc + 2x flags

    hipMemsetAsync(ctr, 0, (512 + 2 * 8 * 1024) * sizeof(unsigned), stream);
    pack_w_kernel<<<dim3(2048), dim3(256), 0, stream>>>(whh, Wp);

    void* args[] = { (void*)&x, (void*)&whx, (void*)&Wp, (void*)&bh, (void*)&wph,
                     (void*)&bp, (void*)&h0, (void*)&h1, (void*)&ctr, (void*)&out };
    hipLaunchCooperativeKernel((const void*)rnn_main, dim3(256), dim3(256),
                               args, 0, stream);
}